// Round 4
// baseline (3199.834 us; speedup 1.0000x reference)
//
#include <hip/hip_runtime.h>

// ---------------------------------------------------------------------------
// GCN 2-layer: out = A_n @ relu(A_n @ (x W1) + b1) W2 + b2,  A_n = D^-1/2 A D^-1/2
// N=50000 nodes, E=800000 edges (+ implicit self loops), F: 128 -> 128 -> 64.
// CSR by dst (count -> scan -> fill), dense fp32 GEMMs, wave-per-node gather:
//   out_v = d_v*(sum_e d_s h_s + d_v h_v) + b
// NOTE: harness delivers integer inputs as int32 (NOT the reference's int64).
// ---------------------------------------------------------------------------

#define N_NODES 50000
#define N_EDGES 800000

// workspace layout (bytes, all 256-aligned)
static constexpr size_t OFF_DEG  = 0;         // int[50000]
static constexpr size_t OFF_CUR  = 200192;    // int[50000]
static constexpr size_t OFF_ROW  = 400384;    // int[50001]
static constexpr size_t OFF_BS   = 600576;    // int[256]
static constexpr size_t OFF_DINV = 601600;    // float[50000]
static constexpr size_t OFF_CSR  = 801792;    // int[800000]
static constexpr size_t OFF_H1   = 4001792;   // float[50000*128]  (reused as h2)
static constexpr size_t OFF_OUT1 = 29601792;  // float[50000*128]
// total ~55.2 MB

__global__ __launch_bounds__(256) void count_deg_k(const int* __restrict__ ei,
                                                   int* __restrict__ deg) {
    int e = blockIdx.x * 256 + threadIdx.x;
    if (e < N_EDGES) {
        int d = ei[N_EDGES + e];
        if ((unsigned)d < N_NODES) atomicAdd(&deg[d], 1);
    }
}

__global__ __launch_bounds__(256) void dinv_k(const int* __restrict__ deg,
                                              float* __restrict__ dinv) {
    int i = blockIdx.x * 256 + threadIdx.x;
    if (i < N_NODES) dinv[i] = rsqrtf((float)(deg[i] + 1));  // +1 self loop
}

__global__ __launch_bounds__(256) void scan1_k(const int* __restrict__ deg,
                                               int* __restrict__ row_start,
                                               int* __restrict__ bsums) {
    __shared__ int sm[256];
    int tid = threadIdx.x;
    int i = blockIdx.x * 256 + tid;
    int v = (i < N_NODES) ? deg[i] : 0;
    sm[tid] = v;
    __syncthreads();
    #pragma unroll
    for (int off = 1; off < 256; off <<= 1) {
        int t = (tid >= off) ? sm[tid - off] : 0;
        __syncthreads();
        sm[tid] += t;
        __syncthreads();
    }
    if (i < N_NODES) row_start[i] = sm[tid] - v;  // exclusive within block
    if (tid == 255) bsums[blockIdx.x] = sm[255];
}

__global__ __launch_bounds__(256) void scan2_k(int* __restrict__ bsums, int nb) {
    __shared__ int sm[256];
    int tid = threadIdx.x;
    int v = (tid < nb) ? bsums[tid] : 0;
    sm[tid] = v;
    __syncthreads();
    #pragma unroll
    for (int off = 1; off < 256; off <<= 1) {
        int t = (tid >= off) ? sm[tid - off] : 0;
        __syncthreads();
        sm[tid] += t;
        __syncthreads();
    }
    if (tid < nb) bsums[tid] = sm[tid] - v;  // exclusive block offsets
}

__global__ __launch_bounds__(256) void scan3_k(int* __restrict__ row_start,
                                               const int* __restrict__ bsums) {
    int i = blockIdx.x * 256 + threadIdx.x;
    if (i < N_NODES) row_start[i] += bsums[blockIdx.x];
    if (i == 0) row_start[N_NODES] = N_EDGES;
}

__global__ __launch_bounds__(256) void fill_k(const int* __restrict__ ei,
                                              const int* __restrict__ row_start,
                                              int* __restrict__ cursor,
                                              int* __restrict__ csr_src) {
    int e = blockIdx.x * 256 + threadIdx.x;
    if (e < N_EDGES) {
        int s = ei[e];
        int d = ei[N_EDGES + e];
        if ((unsigned)d < N_NODES && (unsigned)s < N_NODES) {
            int pos = row_start[d] + atomicAdd(&cursor[d], 1);
            if ((unsigned)pos < N_EDGES) csr_src[pos] = s;
        }
    }
}

// ---------------------------------------------------------------------------
// fp32 GEMM: C[M][BN] = A[M][128] * B[128][BN].  BM=128, BK=32, 256 thr,
// per-thread 8 x (BN/16).  Double-buffered LDS, A stored transposed.
// ---------------------------------------------------------------------------
template <int BN>
__global__ __launch_bounds__(256) void gemm_k128(const float* __restrict__ A,
                                                 const float* __restrict__ B,
                                                 float* __restrict__ C, int M) {
    constexpr int BM = 128, BK = 32, K = 128;
    constexpr int TN = BN / 16;                 // 8 or 4
    constexpr int PA = 4;
    constexpr int BPASS = (BN == 128) ? 4 : 2;

    __shared__ float AsT[2][BK][BM + PA];
    __shared__ float Bs[2][BK][BN];

    const int tid = threadIdx.x;
    const int ty = tid >> 4, tx = tid & 15;
    const int m0 = ty * 8, n0 = tx * TN;
    const int blockM = blockIdx.x * BM;

    float acc[8][TN];
    #pragma unroll
    for (int i = 0; i < 8; ++i)
        #pragma unroll
        for (int j = 0; j < TN; ++j) acc[i][j] = 0.f;

    float4 aReg[4], bReg[BPASS];

    auto loadA = [&](int c) {
        #pragma unroll
        for (int p = 0; p < 4; ++p) {
            int row = blockM + (tid >> 3) + p * 32;
            row = row < M ? row : M - 1;
            aReg[p] = *(const float4*)&A[(size_t)row * K + c * BK + (tid & 7) * 4];
        }
    };
    auto storeA = [&](int buf) {
        #pragma unroll
        for (int p = 0; p < 4; ++p) {
            int kq = (tid & 7) * 4, m = (tid >> 3) + p * 32;
            AsT[buf][kq + 0][m] = aReg[p].x;
            AsT[buf][kq + 1][m] = aReg[p].y;
            AsT[buf][kq + 2][m] = aReg[p].z;
            AsT[buf][kq + 3][m] = aReg[p].w;
        }
    };
    auto loadB = [&](int c) {
        #pragma unroll
        for (int p = 0; p < BPASS; ++p) {
            int k, nq;
            if constexpr (BN == 128) { k = (tid >> 5) + p * 8;  nq = (tid & 31) * 4; }
            else                     { k = (tid >> 4) + p * 16; nq = (tid & 15) * 4; }
            bReg[p] = *(const float4*)&B[(size_t)(c * BK + k) * BN + nq];
        }
    };
    auto storeB = [&](int buf) {
        #pragma unroll
        for (int p = 0; p < BPASS; ++p) {
            int k, nq;
            if constexpr (BN == 128) { k = (tid >> 5) + p * 8;  nq = (tid & 31) * 4; }
            else                     { k = (tid >> 4) + p * 16; nq = (tid & 15) * 4; }
            *(float4*)&Bs[buf][k][nq] = bReg[p];
        }
    };
    auto computeC = [&](int buf) {
        #pragma unroll
        for (int k = 0; k < BK; ++k) {
            float a[8], b[TN];
            float4 a0 = *(const float4*)&AsT[buf][k][m0];
            float4 a1 = *(const float4*)&AsT[buf][k][m0 + 4];
            a[0] = a0.x; a[1] = a0.y; a[2] = a0.z; a[3] = a0.w;
            a[4] = a1.x; a[5] = a1.y; a[6] = a1.z; a[7] = a1.w;
            float4 b0 = *(const float4*)&Bs[buf][k][n0];
            b[0] = b0.x; b[1] = b0.y; b[2] = b0.z; b[3] = b0.w;
            if constexpr (TN == 8) {
                float4 b1 = *(const float4*)&Bs[buf][k][n0 + 4];
                b[4] = b1.x; b[5] = b1.y; b[6] = b1.z; b[7] = b1.w;
            }
            #pragma unroll
            for (int i = 0; i < 8; ++i)
                #pragma unroll
                for (int j = 0; j < TN; ++j) acc[i][j] = fmaf(a[i], b[j], acc[i][j]);
        }
    };

    loadA(0); loadB(0); storeA(0); storeB(0);
    __syncthreads();
    #pragma unroll
    for (int c = 0; c < K / BK; ++c) {
        if (c < K / BK - 1) { loadA(c + 1); loadB(c + 1); }
        computeC(c & 1);
        if (c < K / BK - 1) {
            __syncthreads();
            storeA((c + 1) & 1); storeB((c + 1) & 1);
            __syncthreads();
        }
    }

    #pragma unroll
    for (int i = 0; i < 8; ++i) {
        int row = blockM + m0 + i;
        if (row < M) {
            #pragma unroll
            for (int j = 0; j < TN; j += 4) {
                *(float4*)&C[(size_t)row * BN + n0 + j] =
                    make_float4(acc[i][j], acc[i][j + 1], acc[i][j + 2], acc[i][j + 3]);
            }
        }
    }
}

// ---------------------------------------------------------------------------
// Aggregation: one wave (64 lanes) per node.
// F=128: lane holds float2; F=64: lane holds float.
// out_v = d_v * (sum_edges d_s * h_s + d_v * h_v) + bias  [, relu]
// ---------------------------------------------------------------------------
template <int F, bool RELU>
__global__ __launch_bounds__(256) void agg_k(const float* __restrict__ h,
                                             const float* __restrict__ dinv,
                                             const int* __restrict__ row_start,
                                             const int* __restrict__ csr_src,
                                             const float* __restrict__ bias,
                                             float* __restrict__ out) {
    constexpr int VEC = F / 64;  // 2 or 1
    int wid = (blockIdx.x * 256 + threadIdx.x) >> 6;
    int lane = threadIdx.x & 63;
    if (wid >= N_NODES) return;
    int v = wid;
    float dv = dinv[v];

    float acc0, acc1 = 0.f;
    const float* hv = h + (size_t)v * F;
    if constexpr (VEC == 2) {
        float2 t = *(const float2*)&hv[lane * 2];
        acc0 = dv * t.x; acc1 = dv * t.y;
    } else {
        acc0 = dv * hv[lane];
    }

    int e0 = row_start[v], e1 = row_start[v + 1];
    for (int e = e0; e < e1; e += 64) {
        int cnt = min(64, e1 - e);
        int s = 0; float w = 0.f;
        if (lane < cnt) { s = csr_src[e + lane]; w = dinv[s]; }
        for (int j = 0; j < cnt; ++j) {
            int ss = __shfl(s, j);
            float ww = __shfl(w, j);
            const float* hs = h + (size_t)ss * F;
            if constexpr (VEC == 2) {
                float2 t = *(const float2*)&hs[lane * 2];
                acc0 = fmaf(ww, t.x, acc0); acc1 = fmaf(ww, t.y, acc1);
            } else {
                acc0 = fmaf(ww, hs[lane], acc0);
            }
        }
    }

    if constexpr (VEC == 2) {
        float o0 = dv * acc0 + bias[lane * 2];
        float o1 = dv * acc1 + bias[lane * 2 + 1];
        if (RELU) { o0 = fmaxf(o0, 0.f); o1 = fmaxf(o1, 0.f); }
        *(float2*)&out[(size_t)v * F + lane * 2] = make_float2(o0, o1);
    } else {
        float o0 = dv * acc0 + bias[lane];
        if (RELU) o0 = fmaxf(o0, 0.f);
        out[(size_t)v * F + lane] = o0;
    }
}

extern "C" void kernel_launch(void* const* d_in, const int* in_sizes, int n_in,
                              void* d_out, int out_size, void* d_ws, size_t ws_size,
                              hipStream_t stream) {
    const float* x        = (const float*)d_in[0];   // [50000,128]
    const float* W1       = (const float*)d_in[1];   // [128,128]
    const float* b1       = (const float*)d_in[2];   // [128]
    const float* W2       = (const float*)d_in[3];   // [128,64]
    const float* b2       = (const float*)d_in[4];   // [64]
    const int*   ei       = (const int*)d_in[5];     // [2,800000] delivered as int32
    float* out = (float*)d_out;                      // [50000,64]

    char* ws = (char*)d_ws;
    int*   deg       = (int*)(ws + OFF_DEG);
    int*   cursor    = (int*)(ws + OFF_CUR);
    int*   row_start = (int*)(ws + OFF_ROW);
    int*   bsums     = (int*)(ws + OFF_BS);
    float* dinv      = (float*)(ws + OFF_DINV);
    int*   csr_src   = (int*)(ws + OFF_CSR);
    float* h1        = (float*)(ws + OFF_H1);
    float* out1      = (float*)(ws + OFF_OUT1);
    float* h2        = (float*)(ws + OFF_H1);  // reuse: h1 dead after agg1

    // zero deg + cursor
    hipMemsetAsync(ws + OFF_DEG, 0, OFF_ROW - OFF_DEG, stream);

    const int nbE = (N_EDGES + 255) / 256;   // 3125
    const int nbN = (N_NODES + 255) / 256;   // 196

    count_deg_k<<<nbE, 256, 0, stream>>>(ei, deg);
    dinv_k<<<nbN, 256, 0, stream>>>(deg, dinv);
    scan1_k<<<nbN, 256, 0, stream>>>(deg, row_start, bsums);
    scan2_k<<<1, 256, 0, stream>>>(bsums, nbN);
    scan3_k<<<nbN, 256, 0, stream>>>(row_start, bsums);
    fill_k<<<nbE, 256, 0, stream>>>(ei, row_start, cursor, csr_src);

    const int gemmBlocks = (N_NODES + 127) / 128;  // 391
    gemm_k128<128><<<gemmBlocks, 256, 0, stream>>>(x, W1, h1, N_NODES);
    agg_k<128, true><<<(N_NODES + 3) / 4, 256, 0, stream>>>(h1, dinv, row_start, csr_src, b1, out1);
    gemm_k128<64><<<gemmBlocks, 256, 0, stream>>>(out1, W2, h2, N_NODES);
    agg_k<64, false><<<(N_NODES + 3) / 4, 256, 0, stream>>>(h2, dinv, row_start, csr_src, b2, out);
}

// Round 5
// 338.985 us; speedup vs baseline: 9.4395x; 9.4395x over previous
//
#include <hip/hip_runtime.h>

// ---------------------------------------------------------------------------
// GCN 2-layer: out = A_n @ relu(A_n @ (x W1) + b1) W2 + b2,  A_n = D^-1/2 A D^-1/2
// N=50000 nodes, E=800000 edges (+ implicit self loops), F: 128 -> 128 -> 64.
// CSR by dst (count -> scan -> fill), dense fp32 GEMMs, wave-per-node gather:
//   out_v = d_v*(sum_e d_s h_s + d_v h_v) + b
// R4 lesson: full-unroll + deep staging spilled to scratch (VGPR=256 cap,
// 2.29GB fetch/dispatch, VALUBusy 0.9%). GEMM rebuilt: BK=16, 16 stage regs,
// single barrier per K-step, no full unroll.
// ---------------------------------------------------------------------------

#define N_NODES 50000
#define N_EDGES 800000

// workspace layout (bytes, all 256-aligned)
static constexpr size_t OFF_DEG  = 0;         // int[50000]
static constexpr size_t OFF_CUR  = 200192;    // int[50000]
static constexpr size_t OFF_ROW  = 400384;    // int[50001]
static constexpr size_t OFF_BS   = 600576;    // int[256]
static constexpr size_t OFF_DINV = 601600;    // float[50000]
static constexpr size_t OFF_CSR  = 801792;    // int[800000]
static constexpr size_t OFF_H1   = 4001792;   // float[50000*128]  (reused as h2)
static constexpr size_t OFF_OUT1 = 29601792;  // float[50000*128]
// total ~55.2 MB

__global__ __launch_bounds__(256) void count_deg_k(const int* __restrict__ ei,
                                                   int* __restrict__ deg) {
    int e = blockIdx.x * 256 + threadIdx.x;
    if (e < N_EDGES) {
        int d = ei[N_EDGES + e];
        if ((unsigned)d < N_NODES) atomicAdd(&deg[d], 1);
    }
}

__global__ __launch_bounds__(256) void dinv_k(const int* __restrict__ deg,
                                              float* __restrict__ dinv) {
    int i = blockIdx.x * 256 + threadIdx.x;
    if (i < N_NODES) dinv[i] = rsqrtf((float)(deg[i] + 1));  // +1 self loop
}

__global__ __launch_bounds__(256) void scan1_k(const int* __restrict__ deg,
                                               int* __restrict__ row_start,
                                               int* __restrict__ bsums) {
    __shared__ int sm[256];
    int tid = threadIdx.x;
    int i = blockIdx.x * 256 + tid;
    int v = (i < N_NODES) ? deg[i] : 0;
    sm[tid] = v;
    __syncthreads();
    #pragma unroll
    for (int off = 1; off < 256; off <<= 1) {
        int t = (tid >= off) ? sm[tid - off] : 0;
        __syncthreads();
        sm[tid] += t;
        __syncthreads();
    }
    if (i < N_NODES) row_start[i] = sm[tid] - v;  // exclusive within block
    if (tid == 255) bsums[blockIdx.x] = sm[255];
}

__global__ __launch_bounds__(256) void scan2_k(int* __restrict__ bsums, int nb) {
    __shared__ int sm[256];
    int tid = threadIdx.x;
    int v = (tid < nb) ? bsums[tid] : 0;
    sm[tid] = v;
    __syncthreads();
    #pragma unroll
    for (int off = 1; off < 256; off <<= 1) {
        int t = (tid >= off) ? sm[tid - off] : 0;
        __syncthreads();
        sm[tid] += t;
        __syncthreads();
    }
    if (tid < nb) bsums[tid] = sm[tid] - v;  // exclusive block offsets
}

__global__ __launch_bounds__(256) void scan3_k(int* __restrict__ row_start,
                                               const int* __restrict__ bsums) {
    int i = blockIdx.x * 256 + threadIdx.x;
    if (i < N_NODES) row_start[i] += bsums[blockIdx.x];
    if (i == 0) row_start[N_NODES] = N_EDGES;
}

__global__ __launch_bounds__(256) void fill_k(const int* __restrict__ ei,
                                              const int* __restrict__ row_start,
                                              int* __restrict__ cursor,
                                              int* __restrict__ csr_src) {
    int e = blockIdx.x * 256 + threadIdx.x;
    if (e < N_EDGES) {
        int s = ei[e];
        int d = ei[N_EDGES + e];
        if ((unsigned)d < N_NODES && (unsigned)s < N_NODES) {
            int pos = row_start[d] + atomicAdd(&cursor[d], 1);
            if ((unsigned)pos < N_EDGES) csr_src[pos] = s;
        }
    }
}

// ---------------------------------------------------------------------------
// fp32 GEMM: C[M][BN] = A[M][128] * B[128][BN].  BM=128, BK=16, 256 thr,
// micro-tile 8 x TN (TN=BN/16). Double-buffered LDS, ONE barrier per K-step,
// exactly 4 float4 stage regs per thread. No full-unroll of the K-tile loop.
// ---------------------------------------------------------------------------
template <int BN>
__global__ __launch_bounds__(256) void gemm_k128(const float* __restrict__ A,
                                                 const float* __restrict__ B,
                                                 float* __restrict__ C, int M) {
    constexpr int BM = 128, BK = 16, K = 128;
    constexpr int NT = K / BK;              // 8 K-tiles
    constexpr int TN = BN / 16;             // 8 (BN=128) or 4 (BN=64)
    constexpr int NB = (BN == 128) ? 2 : 1; // B float4 loads per thread

    __shared__ float AsT[2][BK][BM + 4];
    __shared__ float Bs[2][BK][BN];

    const int tid = threadIdx.x;
    const int tx = tid & 15, ty = tid >> 4;
    const int m0 = ty * 8, n0 = tx * TN;
    const int blockM = blockIdx.x * BM;

    const int arow = tid >> 2;         // 0..63
    const int akq  = (tid & 3) * 4;    // k-quad within tile

    float acc[8][TN] = {};
    float4 aS0, aS1, bS0, bS1;

    int r0 = blockM + arow;       r0 = r0 < M ? r0 : M - 1;
    int r1 = blockM + arow + 64;  r1 = r1 < M ? r1 : M - 1;
    const float* Arow0 = A + (size_t)r0 * K + akq;
    const float* Arow1 = A + (size_t)r1 * K + akq;

    auto gload = [&](int kt) {
        aS0 = *(const float4*)&Arow0[kt * BK];
        aS1 = *(const float4*)&Arow1[kt * BK];
        if constexpr (BN == 128) {
            int bk = tid >> 5, bq = (tid & 31) * 4;
            bS0 = *(const float4*)&B[(size_t)(kt * BK + bk) * BN + bq];
            bS1 = *(const float4*)&B[(size_t)(kt * BK + bk + 8) * BN + bq];
        } else {
            int bk = tid >> 4, bq = (tid & 15) * 4;
            bS0 = *(const float4*)&B[(size_t)(kt * BK + bk) * BN + bq];
        }
    };
    auto lstore = [&](int buf) {
        AsT[buf][akq + 0][arow] = aS0.x;
        AsT[buf][akq + 1][arow] = aS0.y;
        AsT[buf][akq + 2][arow] = aS0.z;
        AsT[buf][akq + 3][arow] = aS0.w;
        AsT[buf][akq + 0][arow + 64] = aS1.x;
        AsT[buf][akq + 1][arow + 64] = aS1.y;
        AsT[buf][akq + 2][arow + 64] = aS1.z;
        AsT[buf][akq + 3][arow + 64] = aS1.w;
        if constexpr (BN == 128) {
            int bk = tid >> 5, bq = (tid & 31) * 4;
            *(float4*)&Bs[buf][bk][bq] = bS0;
            *(float4*)&Bs[buf][bk + 8][bq] = bS1;
        } else {
            int bk = tid >> 4, bq = (tid & 15) * 4;
            *(float4*)&Bs[buf][bk][bq] = bS0;
        }
    };
    auto compute = [&](int buf) {
        #pragma unroll
        for (int k = 0; k < BK; ++k) {
            float a[8], b[TN];
            float4 a0 = *(const float4*)&AsT[buf][k][m0];
            float4 a1 = *(const float4*)&AsT[buf][k][m0 + 4];
            a[0] = a0.x; a[1] = a0.y; a[2] = a0.z; a[3] = a0.w;
            a[4] = a1.x; a[5] = a1.y; a[6] = a1.z; a[7] = a1.w;
            float4 b0 = *(const float4*)&Bs[buf][k][n0];
            b[0] = b0.x; b[1] = b0.y; b[2] = b0.z; b[3] = b0.w;
            if constexpr (TN == 8) {
                float4 b1 = *(const float4*)&Bs[buf][k][n0 + 4];
                b[4] = b1.x; b[5] = b1.y; b[6] = b1.z; b[7] = b1.w;
            }
            #pragma unroll
            for (int i = 0; i < 8; ++i)
                #pragma unroll
                for (int j = 0; j < TN; ++j) acc[i][j] = fmaf(a[i], b[j], acc[i][j]);
        }
    };

    gload(0);
    lstore(0);
    __syncthreads();
    #pragma unroll 2
    for (int kt = 0; kt < NT; ++kt) {
        if (kt + 1 < NT) gload(kt + 1);
        compute(kt & 1);
        if (kt + 1 < NT) {
            // safe: buf^1 was last read in iteration kt-1, whose readers all
            // passed the previous barrier before anyone entered iteration kt.
            lstore((kt + 1) & 1);
            __syncthreads();
        }
    }

    #pragma unroll
    for (int i = 0; i < 8; ++i) {
        int row = blockM + m0 + i;
        if (row < M) {
            #pragma unroll
            for (int j = 0; j < TN; j += 4) {
                *(float4*)&C[(size_t)row * BN + n0 + j] =
                    make_float4(acc[i][j], acc[i][j + 1], acc[i][j + 2], acc[i][j + 3]);
            }
        }
    }
}

// ---------------------------------------------------------------------------
// Aggregation: one wave (64 lanes) per node.
// F=128: lane holds float2; F=64: lane holds float.
// out_v = d_v * (sum_edges d_s * h_s + d_v * h_v) + bias  [, relu]
// ---------------------------------------------------------------------------
template <int F, bool RELU>
__global__ __launch_bounds__(256) void agg_k(const float* __restrict__ h,
                                             const float* __restrict__ dinv,
                                             const int* __restrict__ row_start,
                                             const int* __restrict__ csr_src,
                                             const float* __restrict__ bias,
                                             float* __restrict__ out) {
    constexpr int VEC = F / 64;  // 2 or 1
    int wid = (blockIdx.x * 256 + threadIdx.x) >> 6;
    int lane = threadIdx.x & 63;
    if (wid >= N_NODES) return;
    int v = wid;
    float dv = dinv[v];

    float acc0, acc1 = 0.f;
    const float* hv = h + (size_t)v * F;
    if constexpr (VEC == 2) {
        float2 t = *(const float2*)&hv[lane * 2];
        acc0 = dv * t.x; acc1 = dv * t.y;
    } else {
        acc0 = dv * hv[lane];
    }

    int e0 = row_start[v], e1 = row_start[v + 1];
    for (int e = e0; e < e1; e += 64) {
        int cnt = min(64, e1 - e);
        int s = 0; float w = 0.f;
        if (lane < cnt) { s = csr_src[e + lane]; w = dinv[s]; }
        for (int j = 0; j < cnt; ++j) {
            int ss = __shfl(s, j);
            float ww = __shfl(w, j);
            const float* hs = h + (size_t)ss * F;
            if constexpr (VEC == 2) {
                float2 t = *(const float2*)&hs[lane * 2];
                acc0 = fmaf(ww, t.x, acc0); acc1 = fmaf(ww, t.y, acc1);
            } else {
                acc0 = fmaf(ww, hs[lane], acc0);
            }
        }
    }

    if constexpr (VEC == 2) {
        float o0 = dv * acc0 + bias[lane * 2];
        float o1 = dv * acc1 + bias[lane * 2 + 1];
        if (RELU) { o0 = fmaxf(o0, 0.f); o1 = fmaxf(o1, 0.f); }
        *(float2*)&out[(size_t)v * F + lane * 2] = make_float2(o0, o1);
    } else {
        float o0 = dv * acc0 + bias[lane];
        if (RELU) o0 = fmaxf(o0, 0.f);
        out[(size_t)v * F + lane] = o0;
    }
}

extern "C" void kernel_launch(void* const* d_in, const int* in_sizes, int n_in,
                              void* d_out, int out_size, void* d_ws, size_t ws_size,
                              hipStream_t stream) {
    const float* x        = (const float*)d_in[0];   // [50000,128]
    const float* W1       = (const float*)d_in[1];   // [128,128]
    const float* b1       = (const float*)d_in[2];   // [128]
    const float* W2       = (const float*)d_in[3];   // [128,64]
    const float* b2       = (const float*)d_in[4];   // [64]
    const int*   ei       = (const int*)d_in[5];     // [2,800000] delivered as int32
    float* out = (float*)d_out;                      // [50000,64]

    char* ws = (char*)d_ws;
    int*   deg       = (int*)(ws + OFF_DEG);
    int*   cursor    = (int*)(ws + OFF_CUR);
    int*   row_start = (int*)(ws + OFF_ROW);
    int*   bsums     = (int*)(ws + OFF_BS);
    float* dinv      = (float*)(ws + OFF_DINV);
    int*   csr_src   = (int*)(ws + OFF_CSR);
    float* h1        = (float*)(ws + OFF_H1);
    float* out1      = (float*)(ws + OFF_OUT1);
    float* h2        = (float*)(ws + OFF_H1);  // reuse: h1 dead after agg1

    // zero deg + cursor
    hipMemsetAsync(ws + OFF_DEG, 0, OFF_ROW - OFF_DEG, stream);

    const int nbE = (N_EDGES + 255) / 256;   // 3125
    const int nbN = (N_NODES + 255) / 256;   // 196

    count_deg_k<<<nbE, 256, 0, stream>>>(ei, deg);
    dinv_k<<<nbN, 256, 0, stream>>>(deg, dinv);
    scan1_k<<<nbN, 256, 0, stream>>>(deg, row_start, bsums);
    scan2_k<<<1, 256, 0, stream>>>(bsums, nbN);
    scan3_k<<<nbN, 256, 0, stream>>>(row_start, bsums);
    fill_k<<<nbE, 256, 0, stream>>>(ei, row_start, cursor, csr_src);

    const int gemmBlocks = (N_NODES + 127) / 128;  // 391
    gemm_k128<128><<<gemmBlocks, 256, 0, stream>>>(x, W1, h1, N_NODES);
    agg_k<128, true><<<(N_NODES + 3) / 4, 256, 0, stream>>>(h1, dinv, row_start, csr_src, b1, out1);
    gemm_k128<64><<<gemmBlocks, 256, 0, stream>>>(out1, W2, h2, N_NODES);
    agg_k<64, false><<<(N_NODES + 3) / 4, 256, 0, stream>>>(h2, dinv, row_start, csr_src, b2, out);
}